// Round 5
// baseline (262.559 us; speedup 1.0000x reference)
//
#include <hip/hip_runtime.h>
#include <hip/hip_bf16.h>
#include <math.h>

#define S_LEN 2048
#define D_MODEL 2048
#define Q_HEADS 32
#define KV_HEADS 8

typedef __attribute__((ext_vector_type(8))) short short8;   // 8 bf16 = 4 VGPRs
typedef __attribute__((ext_vector_type(4))) float f32x4;

// ---------------------------------------------------------------------------
// helpers
// ---------------------------------------------------------------------------
__device__ __forceinline__ short bf16_rne(float f) {
  unsigned u = __float_as_uint(f);
  unsigned r = (u + 0x7FFFu + ((u >> 16) & 1u)) >> 16;
  return (short)r;
}
// async global->LDS DMA, 16B per lane; lds dest = wave-uniform base + lane*16
__device__ __forceinline__ void dma16(const short* g, short* l) {
  __builtin_amdgcn_global_load_lds(
      (const __attribute__((address_space(1))) void*)g,
      (__attribute__((address_space(3))) void*)l, 16, 0, 0);
}
// hw trig on fp32 theta (radians) via fp64 range reduction to revolutions
__device__ __forceinline__ void fast_sincos(float theta, float& sn, float& cs) {
  double rev = (double)theta * 0.15915494309189535;  // theta / 2pi
  float fr = (float)(rev - floor(rev));
  sn = __builtin_amdgcn_sinf(fr);
  cs = __builtin_amdgcn_cosf(fr);
}
__device__ __forceinline__ void cvt8(const float* src, short* dst, int i) {
  float4 a = *(const float4*)&src[i];
  float4 b = *(const float4*)&src[i + 4];
  short8 h;
  h[0] = bf16_rne(a.x); h[1] = bf16_rne(a.y);
  h[2] = bf16_rne(a.z); h[3] = bf16_rne(a.w);
  h[4] = bf16_rne(b.x); h[5] = bf16_rne(b.y);
  h[6] = bf16_rne(b.z); h[7] = bf16_rne(b.w);
  *(short8*)&dst[i] = h;
}

// ---------------------------------------------------------------------------
// Fused fp32->bf16 conversion of x, W_q, W_kv, W_out in ONE launch.
// Block 0 additionally computes the 32 RoPE frequencies.
// ---------------------------------------------------------------------------
#define NM (2048 * 2048)
#define NKV (1024 * 2048)

__global__ __launch_bounds__(256) void cvt_all(
    const float* __restrict__ x,    short* __restrict__ xh,
    const float* __restrict__ wq,   short* __restrict__ wqh,
    const float* __restrict__ wkv,  short* __restrict__ wkvh,
    const float* __restrict__ wo,   short* __restrict__ woh,
    float* __restrict__ freqTab) {
  if (blockIdx.x == 0 && threadIdx.x < 32) {
    const double e = (2.0 * threadIdx.x) / 64.0;
    freqTab[threadIdx.x] = (float)pow(10000.0, -e);
  }
  int i = (blockIdx.x * 256 + threadIdx.x) * 8;
  if (i < NM) { cvt8(x, xh, i); return; }
  i -= NM;
  if (i < NM) { cvt8(wq, wqh, i); return; }
  i -= NM;
  if (i < NKV) { cvt8(wkv, wkvh, i); return; }
  i -= NKV;
  cvt8(wo, woh, i);
}

// ---------------------------------------------------------------------------
// QKV projection GEMM with FUSED RoPE + pack epilogue. BM=128 BN=64.
// ---------------------------------------------------------------------------
#define QSCALE 0.18033688011112042f   // (1/8) * log2(e)

__global__ __launch_bounds__(256) void gemm_qkv_rope(
    const short* __restrict__ Ah,
    const short* __restrict__ Bq, const short* __restrict__ Bkv,
    const float* __restrict__ bq, const float* __restrict__ bkv,
    const float* __restrict__ tab,
    short* __restrict__ Qrm, short* __restrict__ Krm,
    short* __restrict__ Vt) {
  const int Nq = 2048, K = 2048;
  __shared__ short As[2][128 * 32];
  __shared__ short Bs[2][64 * 32];
  const int tid = threadIdx.x;
  const int w = tid >> 6, lane = tid & 63;
  const int l16 = lane & 15, quad = lane >> 4;

  // XCD-aware 2D decode: 8 regions of 12x x 8y
  const int b = blockIdx.x;
  const int r = b & 7, ri = b >> 3;          // region = XCD, index in region
  const int bx = (r & 3) * 12 + ri % 12;     // 0..47
  const int by = (r >> 2) * 8 + ri / 12;     // 0..15
  const int bm = by * 128;
  const int bnG = bx * 64;

  const short* Bsrc; const float* bias; int bn;
  if (bnG < Nq) { Bsrc = Bq;  bias = bq;  bn = bnG; }
  else          { Bsrc = Bkv; bias = bkv; bn = bnG - Nq; }
  const int mode = (bnG < Nq) ? 0 : ((bnG < Nq + 512) ? 1 : 2);

  const int drow0 = w * 16 + (lane >> 2);
  const int drow1 = drow0 + 64;
  const int slot = lane & 3;
  const int ch0 = slot ^ ((drow0 >> 1) & 3);
  const int ch1 = slot ^ ((drow1 >> 1) & 3);
  const size_t a0 = (size_t)(bm + drow0) * K + ch0 * 8;
  const size_t a1 = (size_t)(bm + drow1) * K + ch1 * 8;
  const size_t b0 = (size_t)(bn + drow0) * K + ch0 * 8;
  const int dA0 = (w * 16) * 32, dA1 = (64 + w * 16) * 32;

  const int wm = (w & 1) * 64, wn = (w >> 1) * 32;
  int offA[4], offB[2];
#pragma unroll
  for (int i = 0; i < 4; ++i) {
    int R = wm + i * 16 + l16;
    offA[i] = R * 32 + (quad ^ ((R >> 1) & 3)) * 8;
  }
#pragma unroll
  for (int j = 0; j < 2; ++j) {
    int R = wn + j * 16 + l16;
    offB[j] = R * 32 + (quad ^ ((R >> 1) & 3)) * 8;
  }

  f32x4 acc[4][2];
#pragma unroll
  for (int i = 0; i < 4; ++i)
#pragma unroll
    for (int j = 0; j < 2; ++j)
#pragma unroll
      for (int e = 0; e < 4; ++e) acc[i][j][e] = 0.f;

  const int T = K / 32;
  dma16(Ah + a0, &As[0][dA0]);
  dma16(Ah + a1, &As[0][dA1]);
  dma16(Bsrc + b0, &Bs[0][dA0]);
  __syncthreads();

  for (int t = 0; t < T; ++t) {
    const int cur = t & 1, nxt = cur ^ 1;
    if (t + 1 < T) {
      const int ko = (t + 1) * 32;
      dma16(Ah + a0 + ko, &As[nxt][dA0]);
      dma16(Ah + a1 + ko, &As[nxt][dA1]);
      dma16(Bsrc + b0 + ko, &Bs[nxt][dA0]);
    }
    short8 af[4], bf[2];
#pragma unroll
    for (int i = 0; i < 4; ++i) af[i] = *(const short8*)&As[cur][offA[i]];
#pragma unroll
    for (int j = 0; j < 2; ++j) bf[j] = *(const short8*)&Bs[cur][offB[j]];
#pragma unroll
    for (int i = 0; i < 4; ++i)
#pragma unroll
      for (int j = 0; j < 2; ++j)
        acc[i][j] = __builtin_amdgcn_mfma_f32_16x16x32_bf16(af[i], bf[j], acc[i][j], 0, 0, 0);
    __syncthreads();
  }

  // ---- fused epilogue (RoPE via lane^1 exchange; V transpose free) ----
#pragma unroll
  for (int i = 0; i < 4; ++i) {
    const int row0 = bm + wm + i * 16 + quad * 4;
#pragma unroll
    for (int j = 0; j < 2; ++j) {
      const int col = bn + wn + j * 16 + l16;
      const float bv = bias[col];
      if (mode == 2) {
        const int d = col - 512;
        short4 sv;
        sv.x = bf16_rne(acc[i][j][0] + bv);
        sv.y = bf16_rne(acc[i][j][1] + bv);
        sv.z = bf16_rne(acc[i][j][2] + bv);
        sv.w = bf16_rne(acc[i][j][3] + bv);
        *(short4*)&Vt[(size_t)d * S_LEN + row0] = sv;
      } else {
        const float fr = tab[(col & 63) >> 1];
        const float sgn = (col & 1) ? 1.f : -1.f;
#pragma unroll
        for (int e = 0; e < 4; ++e) {
          float v = acc[i][j][e] + bv;
          float other = __shfl_xor(v, 1);
          float sn, cs;
          fast_sincos((float)(row0 + e) * fr, sn, cs);
          const float o = v * cs + sgn * other * sn;
          if (mode == 0)
            Qrm[(size_t)(row0 + e) * D_MODEL + col] = bf16_rne(o * QSCALE);
          else
            Krm[(size_t)(row0 + e) * 512 + col] = bf16_rne(o);
        }
      }
    }
  }
}

// ---------------------------------------------------------------------------
// Single-output bf16 NT GEMM, BM=BN=128 (out-projection).
// ---------------------------------------------------------------------------
__global__ __launch_bounds__(256) void gemm_nt1_big(
    const short* __restrict__ A, const short* __restrict__ B,
    const float* __restrict__ bias, float* __restrict__ C,
    int N, int K) {
  __shared__ short As[2][128 * 32];
  __shared__ short Bs[2][128 * 32];
  const int tid = threadIdx.x;
  const int w = tid >> 6, lane = tid & 63;
  const int l16 = lane & 15, quad = lane >> 4;

  const int b = blockIdx.x;
  const int r = b & 7, ri = b >> 3;          // region = XCD
  const int bx = (r & 1) * 8 + ri % 8;       // 0..15
  const int by = (r >> 1) * 4 + ri / 8;      // 0..15
  const int bm = by * 128;
  const int bn = bx * 128;

  const int drow0 = w * 16 + (lane >> 2);
  const int drow1 = drow0 + 64;
  const int slot = lane & 3;
  const int ch0 = slot ^ ((drow0 >> 1) & 3);
  const int ch1 = slot ^ ((drow1 >> 1) & 3);
  const short* gA0 = &A[(size_t)(bm + drow0) * K + ch0 * 8];
  const short* gA1 = &A[(size_t)(bm + drow1) * K + ch1 * 8];
  const short* gB0 = &B[(size_t)(bn + drow0) * K + ch0 * 8];
  const short* gB1 = &B[(size_t)(bn + drow1) * K + ch1 * 8];
  const int dA0 = (w * 16) * 32, dA1 = (64 + w * 16) * 32;

  const int wm = (w & 1) * 64, wn = (w >> 1) * 64;
  int offA[4], offB[4];
#pragma unroll
  for (int i = 0; i < 4; ++i) {
    int R = wm + i * 16 + l16;
    offA[i] = R * 32 + (quad ^ ((R >> 1) & 3)) * 8;
    int Rb = wn + i * 16 + l16;
    offB[i] = Rb * 32 + (quad ^ ((Rb >> 1) & 3)) * 8;
  }

  f32x4 acc[4][4];
#pragma unroll
  for (int i = 0; i < 4; ++i)
#pragma unroll
    for (int j = 0; j < 4; ++j)
#pragma unroll
      for (int e = 0; e < 4; ++e) acc[i][j][e] = 0.f;

  const int T = K / 32;
  dma16(gA0, &As[0][dA0]);
  dma16(gA1, &As[0][dA1]);
  dma16(gB0, &Bs[0][dA0]);
  dma16(gB1, &Bs[0][dA1]);
  __syncthreads();

  for (int t = 0; t < T; ++t) {
    const int cur = t & 1, nxt = cur ^ 1;
    if (t + 1 < T) {
      const int ko = (t + 1) * 32;
      dma16(gA0 + ko, &As[nxt][dA0]);
      dma16(gA1 + ko, &As[nxt][dA1]);
      dma16(gB0 + ko, &Bs[nxt][dA0]);
      dma16(gB1 + ko, &Bs[nxt][dA1]);
    }
    short8 af[4], bf[4];
#pragma unroll
    for (int i = 0; i < 4; ++i) af[i] = *(const short8*)&As[cur][offA[i]];
#pragma unroll
    for (int j = 0; j < 4; ++j) bf[j] = *(const short8*)&Bs[cur][offB[j]];
#pragma unroll
    for (int i = 0; i < 4; ++i)
#pragma unroll
      for (int j = 0; j < 4; ++j)
        acc[i][j] = __builtin_amdgcn_mfma_f32_16x16x32_bf16(af[i], bf[j], acc[i][j], 0, 0, 0);
    __syncthreads();
  }

#pragma unroll
  for (int i = 0; i < 4; ++i) {
#pragma unroll
    for (int j = 0; j < 4; ++j) {
      const int col = bn + wn + j * 16 + l16;
      const float bv = bias[col];
      const int row0 = bm + wm + i * 16 + quad * 4;
#pragma unroll
      for (int e = 0; e < 4; ++e)
        C[(size_t)(row0 + e) * N + col] = acc[i][j][e] + bv;
    }
  }
}

// ---------------------------------------------------------------------------
// MFMA flash attention v9: KV tile 64 -> 128 (16 iterations, half the
// barriers/fixed costs per unit work), zero-C MFMA init. LDS 80KB -> 2
// blocks/CU (8 waves/CU, same as HK attn structure).
//   K tile  [128 k][64 d]   rows 64-col, chunk key = row&7 (as before)
//   V tile  [64 d][128 k]   rows 128-col, chunk key = row&7, two-base stage
//   Ps      [64 q][128 k]   32 logical slots/row, pswz = (l16&7)<<1
// ---------------------------------------------------------------------------
__global__ __launch_bounds__(256, 2) void flash9(
    const short* __restrict__ Qrm, const short* __restrict__ Krm,
    const short* __restrict__ Vt, short* __restrict__ Oh) {
  const int qt = blockIdx.x, h = blockIdx.y;
  const int kvh = h >> 2;
  const int tid = threadIdx.x;
  const int w = tid >> 6, lane = tid & 63;
  const int l16 = lane & 15, quad = lane >> 4;

  __shared__ short Ks[2][128 * 64];   // 2 x 16KB
  __shared__ short Vs[2][64 * 128];   // 2 x 16KB
  __shared__ short Ps[64 * 128];      // 16KB

  const short* Vh = Vt + (size_t)kvh * 64 * S_LEN;
  const int qr = qt * 64 + w * 16 + l16;

  short8 qf0 = *(const short8*)&Qrm[(size_t)qr * D_MODEL + h * 64 + quad * 8];
  short8 qf1 = *(const short8*)&Qrm[(size_t)qr * D_MODEL + h * 64 + 32 + quad * 8];

  short8 ones;
#pragma unroll
  for (int e = 0; e < 8; ++e) ones[e] = (short)0x3F80;   // bf16 1.0

  f32x4 fz;
#pragma unroll
  for (int e = 0; e < 4; ++e) fz[e] = 0.f;

  // ---- staging bases ----
  // K: wave w covers k-rows w*32 .. w*32+31, 4 dma16 (8 rows each).
  //    lane: drow = lane>>3 (row in 8-group), chunk (lane&7)^drow; key=row&7.
  const int drK = lane >> 3;
  const short* gK = &Krm[(size_t)(w * 32 + drK) * 512 + kvh * 64 +
                         ((lane & 7) ^ drK) * 8];
  // V: wave w covers d-rows w*16 .. w*16+15, 4 dma16 (4 rows each).
  //    key = row&7 = drV ^ (4*(d4&1)) -> two bases.
  const int drV = lane >> 4;
  const short* gVa = &Vh[(size_t)(w * 16 + drV) * S_LEN +
                         (((lane & 15) ^ drV)) * 8];
  const short* gVb = &Vh[(size_t)(w * 16 + drV) * S_LEN +
                         (((lane & 15) ^ drV ^ 4)) * 8];

  // ---- LDS read offsets (shorts) ----
  const int sl0 = quad ^ (l16 & 7);
  int offK[8][2];
#pragma unroll
  for (int m = 0; m < 8; ++m) {
    offK[m][0] = (m * 16 + l16) * 64 + sl0 * 8;
    offK[m][1] = (m * 16 + l16) * 64 + (sl0 ^ 4) * 8;
  }
  int offV[4][4];
#pragma unroll
  for (int m = 0; m < 4; ++m)
#pragma unroll
    for (int ks = 0; ks < 4; ++ks)
      offV[m][ks] = (m * 16 + l16) * 128 + ((4 * ks + quad) ^ (l16 & 7)) * 8;

  const int prow = (w * 16 + l16) * 128;
  const int pswz = (l16 & 7) << 1;
  int pwr[8];
#pragma unroll
  for (int m = 0; m < 8; ++m) pwr[m] = prow + ((4 * m + quad) ^ pswz) * 4;
  int prd[4];
#pragma unroll
  for (int ks = 0; ks < 4; ++ks)
    prd[ks] = prow + ((8 * ks + 2 * quad) ^ pswz) * 4;

  f32x4 accl;
#pragma unroll
  for (int e = 0; e < 4; ++e) accl[e] = 0.f;
  f32x4 acco[4];
#pragma unroll
  for (int m = 0; m < 4; ++m)
#pragma unroll
    for (int e = 0; e < 4; ++e) acco[m][e] = 0.f;

  // stage tile 0
#pragma unroll
  for (int d8 = 0; d8 < 4; ++d8)
    dma16(gK + d8 * 8 * 512, &Ks[0][(w * 32 + d8 * 8) * 64]);
  dma16(gVa,                &Vs[0][(w * 16 + 0) * 128]);
  dma16(gVb + 4 * S_LEN,    &Vs[0][(w * 16 + 4) * 128]);
  dma16(gVa + 8 * S_LEN,    &Vs[0][(w * 16 + 8) * 128]);
  dma16(gVb + 12 * S_LEN,   &Vs[0][(w * 16 + 12) * 128]);
  __syncthreads();

  for (int t = 0; t < 16; ++t) {
    const int cur = t & 1, nxt = cur ^ 1;
    if (t + 1 < 16) {
      const short* gKn = gK + (size_t)(t + 1) * 128 * 512;
      const short* gVna = gVa + (t + 1) * 128;
      const short* gVnb = gVb + (t + 1) * 128;
#pragma unroll
      for (int d8 = 0; d8 < 4; ++d8)
        dma16(gKn + d8 * 8 * 512, &Ks[nxt][(w * 32 + d8 * 8) * 64]);
      dma16(gVna,              &Vs[nxt][(w * 16 + 0) * 128]);
      dma16(gVnb + 4 * S_LEN,  &Vs[nxt][(w * 16 + 4) * 128]);
      dma16(gVna + 8 * S_LEN,  &Vs[nxt][(w * 16 + 8) * 128]);
      dma16(gVnb + 12 * S_LEN, &Vs[nxt][(w * 16 + 12) * 128]);
    }

    const short* kc = Ks[cur];
    // QK^T + exp2 + pack, fused per m-block (k = 16m + 4*quad + e)
#pragma unroll
    for (int m = 0; m < 8; ++m) {
      short8 k0 = *(const short8*)&kc[offK[m][0]];
      short8 k1 = *(const short8*)&kc[offK[m][1]];
      f32x4 s = __builtin_amdgcn_mfma_f32_16x16x32_bf16(k0, qf0, fz, 0, 0, 0);
      s = __builtin_amdgcn_mfma_f32_16x16x32_bf16(k1, qf1, s, 0, 0, 0);
      float p0 = exp2f(s[0]);
      float p1 = exp2f(s[1]);
      float p2 = exp2f(s[2]);
      float p3 = exp2f(s[3]);
      unsigned u01 = __builtin_amdgcn_perm(__float_as_uint(p1), __float_as_uint(p0), 0x07060302u);
      unsigned u23 = __builtin_amdgcn_perm(__float_as_uint(p3), __float_as_uint(p2), 0x07060302u);
      *(uint2*)&Ps[pwr[m]] = make_uint2(u01, u23);
    }

    short8 pf[4];
#pragma unroll
    for (int ks = 0; ks < 4; ++ks) pf[ks] = *(const short8*)&Ps[prd[ks]];
#pragma unroll
    for (int ks = 0; ks < 4; ++ks)
      accl = __builtin_amdgcn_mfma_f32_16x16x32_bf16(ones, pf[ks], accl, 0, 0, 0);

    const short* vc = Vs[cur];
#pragma unroll
    for (int m = 0; m < 4; ++m) {
#pragma unroll
      for (int ks = 0; ks < 4; ++ks) {
        short8 vf = *(const short8*)&vc[offV[m][ks]];
        acco[m] = __builtin_amdgcn_mfma_f32_16x16x32_bf16(vf, pf[ks], acco[m], 0, 0, 0);
      }
    }

    __syncthreads();
  }

  const float inv = 1.f / accl[0];
#pragma unroll
  for (int m = 0; m < 4; ++m) {
    short4 h4;
    h4.x = bf16_rne(acco[m][0] * inv);
    h4.y = bf16_rne(acco[m][1] * inv);
    h4.z = bf16_rne(acco[m][2] * inv);
    h4.w = bf16_rne(acco[m][3] * inv);
    const size_t base = (size_t)qr * D_MODEL + h * 64 + m * 16 + quad * 4;
    *(short4*)&Oh[base] = h4;
  }
}

// ---------------------------------------------------------------------------
extern "C" void kernel_launch(void* const* d_in, const int* in_sizes, int n_in,
                              void* d_out, int out_size, void* d_ws, size_t ws_size,
                              hipStream_t stream) {
  const float* x     = (const float*)d_in[0];
  const float* W_q   = (const float*)d_in[1];
  const float* b_q   = (const float*)d_in[2];
  const float* W_kv  = (const float*)d_in[3];
  const float* b_kv  = (const float*)d_in[4];
  const float* W_out = (const float*)d_in[5];
  const float* b_out = (const float*)d_in[6];
  float* out = (float*)d_out;

  char* ws = (char*)d_ws;                        // ~41 MB used
  short* xh    = (short*)(ws);                   //  8 MB
  short* Wqh   = (short*)(ws + (8u << 20));      //  8 MB
  short* Wkvh  = (short*)(ws + (16u << 20));     //  4 MB
  short* Woh   = (short*)(ws + (20u << 20));     //  8 MB
  short* Qrm   = (short*)(ws + (28u << 20));     //  8 MB bf16 [2048][2048]
  short* Krm   = (short*)(ws + (36u << 20));     //  2 MB bf16 [2048][512]
  short* Vtb   = (short*)(ws + (38u << 20));     //  2 MB bf16 [8][64][2048]
  float* freqTab = (float*)(ws + (40u << 20));   //  128 B
  short* Ath   = xh;   // x dead after gemm_qkv_rope

  // fused conversion + freq-table launch
  cvt_all<<<7168, 256, 0, stream>>>(x, xh, W_q, Wqh, W_kv, Wkvh, W_out, Woh,
                                    freqTab);

  // QKV projection, XCD-swizzled 1D grid (768 blocks)
  gemm_qkv_rope<<<768, 256, 0, stream>>>(
      xh, Wqh, Wkvh, b_q, b_kv, freqTab, Qrm, Krm, Vtb);

  flash9<<<dim3(S_LEN / 64, Q_HEADS), 256, 0, stream>>>(Qrm, Krm, Vtb, Ath);

  // out-projection, XCD-swizzled 1D grid (256 blocks)
  gemm_nt1_big<<<256, 256, 0, stream>>>(Ath, Woh, b_out, out, 2048, 2048);
}

// Round 9
// 254.436 us; speedup vs baseline: 1.0319x; 1.0319x over previous
//
#include <hip/hip_runtime.h>
#include <hip/hip_bf16.h>
#include <math.h>

#define S_LEN 2048
#define D_MODEL 2048
#define Q_HEADS 32
#define KV_HEADS 8

typedef __attribute__((ext_vector_type(8))) short short8;   // 8 bf16 = 4 VGPRs
typedef __attribute__((ext_vector_type(4))) float f32x4;

// ---------------------------------------------------------------------------
// helpers
// ---------------------------------------------------------------------------
__device__ __forceinline__ short bf16_rne(float f) {
  unsigned u = __float_as_uint(f);
  unsigned r = (u + 0x7FFFu + ((u >> 16) & 1u)) >> 16;
  return (short)r;
}
// async global->LDS DMA, 16B per lane; lds dest = wave-uniform base + lane*16
__device__ __forceinline__ void dma16(const short* g, short* l) {
  __builtin_amdgcn_global_load_lds(
      (const __attribute__((address_space(1))) void*)g,
      (__attribute__((address_space(3))) void*)l, 16, 0, 0);
}
// hw trig on fp32 theta (radians) via fp64 range reduction to revolutions
__device__ __forceinline__ void fast_sincos(float theta, float& sn, float& cs) {
  double rev = (double)theta * 0.15915494309189535;  // theta / 2pi
  float fr = (float)(rev - floor(rev));
  sn = __builtin_amdgcn_sinf(fr);
  cs = __builtin_amdgcn_cosf(fr);
}
__device__ __forceinline__ void cvt8(const float* src, short* dst, int i) {
  float4 a = *(const float4*)&src[i];
  float4 b = *(const float4*)&src[i + 4];
  short8 h;
  h[0] = bf16_rne(a.x); h[1] = bf16_rne(a.y);
  h[2] = bf16_rne(a.z); h[3] = bf16_rne(a.w);
  h[4] = bf16_rne(b.x); h[5] = bf16_rne(b.y);
  h[6] = bf16_rne(b.z); h[7] = bf16_rne(b.w);
  *(short8*)&dst[i] = h;
}

// ---------------------------------------------------------------------------
// Fused fp32->bf16 conversion of x, W_q, W_kv, W_out in ONE launch.
// Block 0 additionally computes the 32 RoPE frequencies.
// ---------------------------------------------------------------------------
#define NM (2048 * 2048)
#define NKV (1024 * 2048)

__global__ __launch_bounds__(256) void cvt_all(
    const float* __restrict__ x,    short* __restrict__ xh,
    const float* __restrict__ wq,   short* __restrict__ wqh,
    const float* __restrict__ wkv,  short* __restrict__ wkvh,
    const float* __restrict__ wo,   short* __restrict__ woh,
    float* __restrict__ freqTab) {
  if (blockIdx.x == 0 && threadIdx.x < 32) {
    const double e = (2.0 * threadIdx.x) / 64.0;
    freqTab[threadIdx.x] = (float)pow(10000.0, -e);
  }
  int i = (blockIdx.x * 256 + threadIdx.x) * 8;
  if (i < NM) { cvt8(x, xh, i); return; }
  i -= NM;
  if (i < NM) { cvt8(wq, wqh, i); return; }
  i -= NM;
  if (i < NKV) { cvt8(wkv, wkvh, i); return; }
  i -= NKV;
  cvt8(wo, woh, i);
}

// ---------------------------------------------------------------------------
// QKV projection GEMM with FUSED RoPE + pack epilogue. BM=128 BN=64.
// ---------------------------------------------------------------------------
#define QSCALE 0.18033688011112042f   // (1/8) * log2(e)

__global__ __launch_bounds__(256) void gemm_qkv_rope(
    const short* __restrict__ Ah,
    const short* __restrict__ Bq, const short* __restrict__ Bkv,
    const float* __restrict__ bq, const float* __restrict__ bkv,
    const float* __restrict__ tab,
    short* __restrict__ Qrm, short* __restrict__ Krm,
    short* __restrict__ Vt) {
  const int Nq = 2048, K = 2048;
  __shared__ short As[2][128 * 32];
  __shared__ short Bs[2][64 * 32];
  const int tid = threadIdx.x;
  const int w = tid >> 6, lane = tid & 63;
  const int l16 = lane & 15, quad = lane >> 4;

  // XCD-aware 2D decode: 8 regions of 12x x 8y
  const int b = blockIdx.x;
  const int r = b & 7, ri = b >> 3;          // region = XCD, index in region
  const int bx = (r & 3) * 12 + ri % 12;     // 0..47
  const int by = (r >> 2) * 8 + ri / 12;     // 0..15
  const int bm = by * 128;
  const int bnG = bx * 64;

  const short* Bsrc; const float* bias; int bn;
  if (bnG < Nq) { Bsrc = Bq;  bias = bq;  bn = bnG; }
  else          { Bsrc = Bkv; bias = bkv; bn = bnG - Nq; }
  const int mode = (bnG < Nq) ? 0 : ((bnG < Nq + 512) ? 1 : 2);

  const int drow0 = w * 16 + (lane >> 2);
  const int drow1 = drow0 + 64;
  const int slot = lane & 3;
  const int ch0 = slot ^ ((drow0 >> 1) & 3);
  const int ch1 = slot ^ ((drow1 >> 1) & 3);
  const size_t a0 = (size_t)(bm + drow0) * K + ch0 * 8;
  const size_t a1 = (size_t)(bm + drow1) * K + ch1 * 8;
  const size_t b0 = (size_t)(bn + drow0) * K + ch0 * 8;
  const int dA0 = (w * 16) * 32, dA1 = (64 + w * 16) * 32;

  const int wm = (w & 1) * 64, wn = (w >> 1) * 32;
  int offA[4], offB[2];
#pragma unroll
  for (int i = 0; i < 4; ++i) {
    int R = wm + i * 16 + l16;
    offA[i] = R * 32 + (quad ^ ((R >> 1) & 3)) * 8;
  }
#pragma unroll
  for (int j = 0; j < 2; ++j) {
    int R = wn + j * 16 + l16;
    offB[j] = R * 32 + (quad ^ ((R >> 1) & 3)) * 8;
  }

  f32x4 acc[4][2];
#pragma unroll
  for (int i = 0; i < 4; ++i)
#pragma unroll
    for (int j = 0; j < 2; ++j)
#pragma unroll
      for (int e = 0; e < 4; ++e) acc[i][j][e] = 0.f;

  const int T = K / 32;
  dma16(Ah + a0, &As[0][dA0]);
  dma16(Ah + a1, &As[0][dA1]);
  dma16(Bsrc + b0, &Bs[0][dA0]);
  __syncthreads();

  for (int t = 0; t < T; ++t) {
    const int cur = t & 1, nxt = cur ^ 1;
    if (t + 1 < T) {
      const int ko = (t + 1) * 32;
      dma16(Ah + a0 + ko, &As[nxt][dA0]);
      dma16(Ah + a1 + ko, &As[nxt][dA1]);
      dma16(Bsrc + b0 + ko, &Bs[nxt][dA0]);
    }
    short8 af[4], bf[2];
#pragma unroll
    for (int i = 0; i < 4; ++i) af[i] = *(const short8*)&As[cur][offA[i]];
#pragma unroll
    for (int j = 0; j < 2; ++j) bf[j] = *(const short8*)&Bs[cur][offB[j]];
#pragma unroll
    for (int i = 0; i < 4; ++i)
#pragma unroll
      for (int j = 0; j < 2; ++j)
        acc[i][j] = __builtin_amdgcn_mfma_f32_16x16x32_bf16(af[i], bf[j], acc[i][j], 0, 0, 0);
    __syncthreads();
  }

  // ---- fused epilogue (RoPE via lane^1 exchange; V transpose free) ----
#pragma unroll
  for (int i = 0; i < 4; ++i) {
    const int row0 = bm + wm + i * 16 + quad * 4;
#pragma unroll
    for (int j = 0; j < 2; ++j) {
      const int col = bn + wn + j * 16 + l16;
      const float bv = bias[col];
      if (mode == 2) {
        const int d = col - 512;
        short4 sv;
        sv.x = bf16_rne(acc[i][j][0] + bv);
        sv.y = bf16_rne(acc[i][j][1] + bv);
        sv.z = bf16_rne(acc[i][j][2] + bv);
        sv.w = bf16_rne(acc[i][j][3] + bv);
        *(short4*)&Vt[(size_t)d * S_LEN + row0] = sv;
      } else {
        const float fr = tab[(col & 63) >> 1];
        const float sgn = (col & 1) ? 1.f : -1.f;
#pragma unroll
        for (int e = 0; e < 4; ++e) {
          float v = acc[i][j][e] + bv;
          float other = __shfl_xor(v, 1);
          float sn, cs;
          fast_sincos((float)(row0 + e) * fr, sn, cs);
          const float o = v * cs + sgn * other * sn;
          if (mode == 0)
            Qrm[(size_t)(row0 + e) * D_MODEL + col] = bf16_rne(o * QSCALE);
          else
            Krm[(size_t)(row0 + e) * 512 + col] = bf16_rne(o);
        }
      }
    }
  }
}

// ---------------------------------------------------------------------------
// Single-output bf16 NT GEMM, BM=BN=128 (out-projection).
// ---------------------------------------------------------------------------
__global__ __launch_bounds__(256) void gemm_nt1_big(
    const short* __restrict__ A, const short* __restrict__ B,
    const float* __restrict__ bias, float* __restrict__ C,
    int N, int K) {
  __shared__ short As[2][128 * 32];
  __shared__ short Bs[2][128 * 32];
  const int tid = threadIdx.x;
  const int w = tid >> 6, lane = tid & 63;
  const int l16 = lane & 15, quad = lane >> 4;

  const int b = blockIdx.x;
  const int r = b & 7, ri = b >> 3;          // region = XCD
  const int bx = (r & 1) * 8 + ri % 8;       // 0..15
  const int by = (r >> 1) * 4 + ri / 8;      // 0..15
  const int bm = by * 128;
  const int bn = bx * 128;

  const int drow0 = w * 16 + (lane >> 2);
  const int drow1 = drow0 + 64;
  const int slot = lane & 3;
  const int ch0 = slot ^ ((drow0 >> 1) & 3);
  const int ch1 = slot ^ ((drow1 >> 1) & 3);
  const short* gA0 = &A[(size_t)(bm + drow0) * K + ch0 * 8];
  const short* gA1 = &A[(size_t)(bm + drow1) * K + ch1 * 8];
  const short* gB0 = &B[(size_t)(bn + drow0) * K + ch0 * 8];
  const short* gB1 = &B[(size_t)(bn + drow1) * K + ch1 * 8];
  const int dA0 = (w * 16) * 32, dA1 = (64 + w * 16) * 32;

  const int wm = (w & 1) * 64, wn = (w >> 1) * 64;
  int offA[4], offB[4];
#pragma unroll
  for (int i = 0; i < 4; ++i) {
    int R = wm + i * 16 + l16;
    offA[i] = R * 32 + (quad ^ ((R >> 1) & 3)) * 8;
    int Rb = wn + i * 16 + l16;
    offB[i] = Rb * 32 + (quad ^ ((Rb >> 1) & 3)) * 8;
  }

  f32x4 acc[4][4];
#pragma unroll
  for (int i = 0; i < 4; ++i)
#pragma unroll
    for (int j = 0; j < 4; ++j)
#pragma unroll
      for (int e = 0; e < 4; ++e) acc[i][j][e] = 0.f;

  const int T = K / 32;
  dma16(gA0, &As[0][dA0]);
  dma16(gA1, &As[0][dA1]);
  dma16(gB0, &Bs[0][dA0]);
  dma16(gB1, &Bs[0][dA1]);
  __syncthreads();

  for (int t = 0; t < T; ++t) {
    const int cur = t & 1, nxt = cur ^ 1;
    if (t + 1 < T) {
      const int ko = (t + 1) * 32;
      dma16(gA0 + ko, &As[nxt][dA0]);
      dma16(gA1 + ko, &As[nxt][dA1]);
      dma16(gB0 + ko, &Bs[nxt][dA0]);
      dma16(gB1 + ko, &Bs[nxt][dA1]);
    }
    short8 af[4], bf[4];
#pragma unroll
    for (int i = 0; i < 4; ++i) af[i] = *(const short8*)&As[cur][offA[i]];
#pragma unroll
    for (int j = 0; j < 4; ++j) bf[j] = *(const short8*)&Bs[cur][offB[j]];
#pragma unroll
    for (int i = 0; i < 4; ++i)
#pragma unroll
      for (int j = 0; j < 4; ++j)
        acc[i][j] = __builtin_amdgcn_mfma_f32_16x16x32_bf16(af[i], bf[j], acc[i][j], 0, 0, 0);
    __syncthreads();
  }

#pragma unroll
  for (int i = 0; i < 4; ++i) {
#pragma unroll
    for (int j = 0; j < 4; ++j) {
      const int col = bn + wn + j * 16 + l16;
      const float bv = bias[col];
      const int row0 = bm + wm + i * 16 + quad * 4;
#pragma unroll
      for (int e = 0; e < 4; ++e)
        C[(size_t)(row0 + e) * N + col] = acc[i][j][e] + bv;
    }
  }
}

// ---------------------------------------------------------------------------
// MFMA flash attention v10 = v8 structure (KV tile 64, 40KB LDS, verified
// 72us) + zero-C MFMA init (no per-tile acc zeroing) + s_setprio around the
// MFMA clusters (T5; co-resident blocks at different phases -> scheduler can
// prefer MFMA-issuing waves).
// ---------------------------------------------------------------------------
__global__ __launch_bounds__(256, 4) void flash10(
    const short* __restrict__ Qrm, const short* __restrict__ Krm,
    const short* __restrict__ Vt, short* __restrict__ Oh) {
  const int qt = blockIdx.x, h = blockIdx.y;
  const int kvh = h >> 2;
  const int tid = threadIdx.x;
  const int w = tid >> 6, lane = tid & 63;
  const int l16 = lane & 15, quad = lane >> 4;

  __shared__ short Ks[2][64 * 64];
  __shared__ short Vs[2][64 * 64];
  __shared__ short Ps[64 * 64];

  const short* Vh = Vt + (size_t)kvh * 64 * S_LEN;
  const int qr = qt * 64 + w * 16 + l16;

  short8 qf0 = *(const short8*)&Qrm[(size_t)qr * D_MODEL + h * 64 + quad * 8];
  short8 qf1 = *(const short8*)&Qrm[(size_t)qr * D_MODEL + h * 64 + 32 + quad * 8];

  short8 ones;
#pragma unroll
  for (int e = 0; e < 8; ++e) ones[e] = (short)0x3F80;   // bf16 1.0

  f32x4 fz;
#pragma unroll
  for (int e = 0; e < 4; ++e) fz[e] = 0.f;

  const int drow = lane >> 3;
  const int ch = (lane & 7) ^ drow;
  const short* gK = &Krm[(size_t)(w * 16 + drow) * 512 + kvh * 64 + ch * 8];
  const short* gV = &Vh[(size_t)(w * 16 + drow) * S_LEN + ch * 8];

  const int sl0 = quad ^ (l16 & 7);
  int offT[4][2];
#pragma unroll
  for (int m = 0; m < 4; ++m) {
    offT[m][0] = (m * 16 + l16) * 64 + sl0 * 8;
    offT[m][1] = (m * 16 + l16) * 64 + (sl0 ^ 4) * 8;
  }

  const int prow = (w * 16 + l16) * 64;
  const int pswz = (l16 & 7) << 1;
  int pwr[4];
#pragma unroll
  for (int m = 0; m < 4; ++m) pwr[m] = prow + ((4 * m + quad) ^ pswz) * 4;
  const int prd0 = prow + ((2 * quad) ^ pswz) * 4;
  const int prd1 = prow + ((8 + 2 * quad) ^ pswz) * 4;

  f32x4 accl;
#pragma unroll
  for (int e = 0; e < 4; ++e) accl[e] = 0.f;
  f32x4 acco[4];
#pragma unroll
  for (int m = 0; m < 4; ++m)
#pragma unroll
    for (int e = 0; e < 4; ++e) acco[m][e] = 0.f;

  dma16(gK,               &Ks[0][(w * 16) * 64]);
  dma16(gK + 8 * 512,     &Ks[0][(w * 16 + 8) * 64]);
  dma16(gV,               &Vs[0][(w * 16) * 64]);
  dma16(gV + 8 * S_LEN,   &Vs[0][(w * 16 + 8) * 64]);
  __syncthreads();

  for (int t = 0; t < 32; ++t) {
    const int cur = t & 1, nxt = cur ^ 1;
    if (t + 1 < 32) {
      const short* gKn = gK + (size_t)(t + 1) * 64 * 512;
      const short* gVn = gV + (t + 1) * 64;
      dma16(gKn,             &Ks[nxt][(w * 16) * 64]);
      dma16(gKn + 8 * 512,   &Ks[nxt][(w * 16 + 8) * 64]);
      dma16(gVn,             &Vs[nxt][(w * 16) * 64]);
      dma16(gVn + 8 * S_LEN, &Vs[nxt][(w * 16 + 8) * 64]);
    }

    const short* kc = Ks[cur];
    f32x4 accs[4];
    __builtin_amdgcn_s_setprio(1);
#pragma unroll
    for (int m = 0; m < 4; ++m) {
      short8 k0 = *(const short8*)&kc[offT[m][0]];
      short8 k1 = *(const short8*)&kc[offT[m][1]];
      accs[m] = __builtin_amdgcn_mfma_f32_16x16x32_bf16(k0, qf0, fz, 0, 0, 0);
      accs[m] = __builtin_amdgcn_mfma_f32_16x16x32_bf16(k1, qf1, accs[m], 0, 0, 0);
    }
    __builtin_amdgcn_s_setprio(0);

#pragma unroll
    for (int m = 0; m < 4; ++m) {
      float p0 = exp2f(accs[m][0]);
      float p1 = exp2f(accs[m][1]);
      float p2 = exp2f(accs[m][2]);
      float p3 = exp2f(accs[m][3]);
      unsigned u01 = __builtin_amdgcn_perm(__float_as_uint(p1), __float_as_uint(p0), 0x07060302u);
      unsigned u23 = __builtin_amdgcn_perm(__float_as_uint(p3), __float_as_uint(p2), 0x07060302u);
      *(uint2*)&Ps[pwr[m]] = make_uint2(u01, u23);
    }

    short8 pf0 = *(const short8*)&Ps[prd0];
    short8 pf1 = *(const short8*)&Ps[prd1];
    __builtin_amdgcn_s_setprio(1);
    accl = __builtin_amdgcn_mfma_f32_16x16x32_bf16(ones, pf0, accl, 0, 0, 0);
    accl = __builtin_amdgcn_mfma_f32_16x16x32_bf16(ones, pf1, accl, 0, 0, 0);
    const short* vc = Vs[cur];
#pragma unroll
    for (int m = 0; m < 4; ++m) {
      short8 v0 = *(const short8*)&vc[offT[m][0]];
      short8 v1 = *(const short8*)&vc[offT[m][1]];
      acco[m] = __builtin_amdgcn_mfma_f32_16x16x32_bf16(v0, pf0, acco[m], 0, 0, 0);
      acco[m] = __builtin_amdgcn_mfma_f32_16x16x32_bf16(v1, pf1, acco[m], 0, 0, 0);
    }
    __builtin_amdgcn_s_setprio(0);

    __syncthreads();
  }

  const float inv = 1.f / accl[0];
#pragma unroll
  for (int m = 0; m < 4; ++m) {
    short4 h4;
    h4.x = bf16_rne(acco[m][0] * inv);
    h4.y = bf16_rne(acco[m][1] * inv);
    h4.z = bf16_rne(acco[m][2] * inv);
    h4.w = bf16_rne(acco[m][3] * inv);
    const size_t base = (size_t)qr * D_MODEL + h * 64 + m * 16 + quad * 4;
    *(short4*)&Oh[base] = h4;
  }
}

// ---------------------------------------------------------------------------
extern "C" void kernel_launch(void* const* d_in, const int* in_sizes, int n_in,
                              void* d_out, int out_size, void* d_ws, size_t ws_size,
                              hipStream_t stream) {
  const float* x     = (const float*)d_in[0];
  const float* W_q   = (const float*)d_in[1];
  const float* b_q   = (const float*)d_in[2];
  const float* W_kv  = (const float*)d_in[3];
  const float* b_kv  = (const float*)d_in[4];
  const float* W_out = (const float*)d_in[5];
  const float* b_out = (const float*)d_in[6];
  float* out = (float*)d_out;

  char* ws = (char*)d_ws;                        // ~41 MB used
  short* xh    = (short*)(ws);                   //  8 MB
  short* Wqh   = (short*)(ws + (8u << 20));      //  8 MB
  short* Wkvh  = (short*)(ws + (16u << 20));     //  4 MB
  short* Woh   = (short*)(ws + (20u << 20));     //  8 MB
  short* Qrm   = (short*)(ws + (28u << 20));     //  8 MB bf16 [2048][2048]
  short* Krm   = (short*)(ws + (36u << 20));     //  2 MB bf16 [2048][512]
  short* Vtb   = (short*)(ws + (38u << 20));     //  2 MB bf16 [8][64][2048]
  float* freqTab = (float*)(ws + (40u << 20));   //  128 B
  short* Ath   = xh;   // x dead after gemm_qkv_rope

  // fused conversion + freq-table launch
  cvt_all<<<7168, 256, 0, stream>>>(x, xh, W_q, Wqh, W_kv, Wkvh, W_out, Woh,
                                    freqTab);

  // QKV projection, XCD-swizzled 1D grid (768 blocks)
  gemm_qkv_rope<<<768, 256, 0, stream>>>(
      xh, Wqh, Wkvh, b_q, b_kv, freqTab, Qrm, Krm, Vtb);

  flash10<<<dim3(S_LEN / 64, Q_HEADS), 256, 0, stream>>>(Qrm, Krm, Vtb, Ath);

  // out-projection, XCD-swizzled 1D grid (256 blocks)
  gemm_nt1_big<<<256, 256, 0, stream>>>(Ath, Woh, b_out, out, 2048, 2048);
}

// Round 12
// 246.044 us; speedup vs baseline: 1.0671x; 1.0341x over previous
//
#include <hip/hip_runtime.h>
#include <hip/hip_bf16.h>
#include <math.h>

#define S_LEN 2048
#define D_MODEL 2048
#define Q_HEADS 32
#define KV_HEADS 8

typedef __attribute__((ext_vector_type(8))) short short8;   // 8 bf16 = 4 VGPRs
typedef __attribute__((ext_vector_type(4))) float f32x4;

// ---------------------------------------------------------------------------
// helpers
// ---------------------------------------------------------------------------
__device__ __forceinline__ short bf16_rne(float f) {
  unsigned u = __float_as_uint(f);
  unsigned r = (u + 0x7FFFu + ((u >> 16) & 1u)) >> 16;
  return (short)r;
}
// async global->LDS DMA, 16B per lane; lds dest = wave-uniform base + lane*16
__device__ __forceinline__ void dma16(const short* g, short* l) {
  __builtin_amdgcn_global_load_lds(
      (const __attribute__((address_space(1))) void*)g,
      (__attribute__((address_space(3))) void*)l, 16, 0, 0);
}
// hw trig on fp32 theta (radians) via fp64 range reduction to revolutions
__device__ __forceinline__ void fast_sincos(float theta, float& sn, float& cs) {
  double rev = (double)theta * 0.15915494309189535;  // theta / 2pi
  float fr = (float)(rev - floor(rev));
  sn = __builtin_amdgcn_sinf(fr);
  cs = __builtin_amdgcn_cosf(fr);
}
__device__ __forceinline__ void cvt8(const float* src, short* dst, int i) {
  float4 a = *(const float4*)&src[i];
  float4 b = *(const float4*)&src[i + 4];
  short8 h;
  h[0] = bf16_rne(a.x); h[1] = bf16_rne(a.y);
  h[2] = bf16_rne(a.z); h[3] = bf16_rne(a.w);
  h[4] = bf16_rne(b.x); h[5] = bf16_rne(b.y);
  h[6] = bf16_rne(b.z); h[7] = bf16_rne(b.w);
  *(short8*)&dst[i] = h;
}

// ---------------------------------------------------------------------------
// Fused fp32->bf16 conversion of x, W_q, W_kv, W_out in ONE launch.
// Block 0 additionally computes the 32 RoPE frequencies.
// ---------------------------------------------------------------------------
#define NM (2048 * 2048)
#define NKV (1024 * 2048)

__global__ __launch_bounds__(256) void cvt_all(
    const float* __restrict__ x,    short* __restrict__ xh,
    const float* __restrict__ wq,   short* __restrict__ wqh,
    const float* __restrict__ wkv,  short* __restrict__ wkvh,
    const float* __restrict__ wo,   short* __restrict__ woh,
    float* __restrict__ freqTab) {
  if (blockIdx.x == 0 && threadIdx.x < 32) {
    const double e = (2.0 * threadIdx.x) / 64.0;
    freqTab[threadIdx.x] = (float)pow(10000.0, -e);
  }
  int i = (blockIdx.x * 256 + threadIdx.x) * 8;
  if (i < NM) { cvt8(x, xh, i); return; }
  i -= NM;
  if (i < NM) { cvt8(wq, wqh, i); return; }
  i -= NM;
  if (i < NKV) { cvt8(wkv, wkvh, i); return; }
  i -= NKV;
  cvt8(wo, woh, i);
}

// ---------------------------------------------------------------------------
// QKV projection GEMM with FUSED RoPE + pack epilogue. BM=128 BN=64.
// ---------------------------------------------------------------------------
#define QSCALE 0.18033688011112042f   // (1/8) * log2(e)

__global__ __launch_bounds__(256) void gemm_qkv_rope(
    const short* __restrict__ Ah,
    const short* __restrict__ Bq, const short* __restrict__ Bkv,
    const float* __restrict__ bq, const float* __restrict__ bkv,
    const float* __restrict__ tab,
    short* __restrict__ Qrm, short* __restrict__ Krm,
    short* __restrict__ Vt) {
  const int Nq = 2048, K = 2048;
  __shared__ short As[2][128 * 32];
  __shared__ short Bs[2][64 * 32];
  const int tid = threadIdx.x;
  const int w = tid >> 6, lane = tid & 63;
  const int l16 = lane & 15, quad = lane >> 4;

  // XCD-aware 2D decode: 8 regions of 12x x 8y
  const int b = blockIdx.x;
  const int r = b & 7, ri = b >> 3;          // region = XCD, index in region
  const int bx = (r & 3) * 12 + ri % 12;     // 0..47
  const int by = (r >> 2) * 8 + ri / 12;     // 0..15
  const int bm = by * 128;
  const int bnG = bx * 64;

  const short* Bsrc; const float* bias; int bn;
  if (bnG < Nq) { Bsrc = Bq;  bias = bq;  bn = bnG; }
  else          { Bsrc = Bkv; bias = bkv; bn = bnG - Nq; }
  const int mode = (bnG < Nq) ? 0 : ((bnG < Nq + 512) ? 1 : 2);

  const int drow0 = w * 16 + (lane >> 2);
  const int drow1 = drow0 + 64;
  const int slot = lane & 3;
  const int ch0 = slot ^ ((drow0 >> 1) & 3);
  const int ch1 = slot ^ ((drow1 >> 1) & 3);
  const size_t a0 = (size_t)(bm + drow0) * K + ch0 * 8;
  const size_t a1 = (size_t)(bm + drow1) * K + ch1 * 8;
  const size_t b0 = (size_t)(bn + drow0) * K + ch0 * 8;
  const int dA0 = (w * 16) * 32, dA1 = (64 + w * 16) * 32;

  const int wm = (w & 1) * 64, wn = (w >> 1) * 32;
  int offA[4], offB[2];
#pragma unroll
  for (int i = 0; i < 4; ++i) {
    int R = wm + i * 16 + l16;
    offA[i] = R * 32 + (quad ^ ((R >> 1) & 3)) * 8;
  }
#pragma unroll
  for (int j = 0; j < 2; ++j) {
    int R = wn + j * 16 + l16;
    offB[j] = R * 32 + (quad ^ ((R >> 1) & 3)) * 8;
  }

  f32x4 acc[4][2];
#pragma unroll
  for (int i = 0; i < 4; ++i)
#pragma unroll
    for (int j = 0; j < 2; ++j)
#pragma unroll
      for (int e = 0; e < 4; ++e) acc[i][j][e] = 0.f;

  const int T = K / 32;
  dma16(Ah + a0, &As[0][dA0]);
  dma16(Ah + a1, &As[0][dA1]);
  dma16(Bsrc + b0, &Bs[0][dA0]);
  __syncthreads();

  for (int t = 0; t < T; ++t) {
    const int cur = t & 1, nxt = cur ^ 1;
    if (t + 1 < T) {
      const int ko = (t + 1) * 32;
      dma16(Ah + a0 + ko, &As[nxt][dA0]);
      dma16(Ah + a1 + ko, &As[nxt][dA1]);
      dma16(Bsrc + b0 + ko, &Bs[nxt][dA0]);
    }
    short8 af[4], bf[2];
#pragma unroll
    for (int i = 0; i < 4; ++i) af[i] = *(const short8*)&As[cur][offA[i]];
#pragma unroll
    for (int j = 0; j < 2; ++j) bf[j] = *(const short8*)&Bs[cur][offB[j]];
#pragma unroll
    for (int i = 0; i < 4; ++i)
#pragma unroll
      for (int j = 0; j < 2; ++j)
        acc[i][j] = __builtin_amdgcn_mfma_f32_16x16x32_bf16(af[i], bf[j], acc[i][j], 0, 0, 0);
    __syncthreads();
  }

  // ---- fused epilogue (RoPE via lane^1 exchange; V transpose free) ----
#pragma unroll
  for (int i = 0; i < 4; ++i) {
    const int row0 = bm + wm + i * 16 + quad * 4;
#pragma unroll
    for (int j = 0; j < 2; ++j) {
      const int col = bn + wn + j * 16 + l16;
      const float bv = bias[col];
      if (mode == 2) {
        const int d = col - 512;
        short4 sv;
        sv.x = bf16_rne(acc[i][j][0] + bv);
        sv.y = bf16_rne(acc[i][j][1] + bv);
        sv.z = bf16_rne(acc[i][j][2] + bv);
        sv.w = bf16_rne(acc[i][j][3] + bv);
        *(short4*)&Vt[(size_t)d * S_LEN + row0] = sv;
      } else {
        const float fr = tab[(col & 63) >> 1];
        const float sgn = (col & 1) ? 1.f : -1.f;
#pragma unroll
        for (int e = 0; e < 4; ++e) {
          float v = acc[i][j][e] + bv;
          float other = __shfl_xor(v, 1);
          float sn, cs;
          fast_sincos((float)(row0 + e) * fr, sn, cs);
          const float o = v * cs + sgn * other * sn;
          if (mode == 0)
            Qrm[(size_t)(row0 + e) * D_MODEL + col] = bf16_rne(o * QSCALE);
          else
            Krm[(size_t)(row0 + e) * 512 + col] = bf16_rne(o);
        }
      }
    }
  }
}

// ---------------------------------------------------------------------------
// Out-projection bf16 NT GEMM v2: BM=128 BN=64, grid 512 -> 2 blocks/CU
// (was 128x128, 256 blocks = 1 block/CU: the per-K-step vmcnt(0)+barrier
// drain had NO co-resident block to overlap with). Mainloop is a clone of
// the verified gemm_qkv_rope loop; epilogue is nt1's fp32+bias store.
// XCD decode: 8 regions of 8x x 8y (bijective for 512 blocks).
// ---------------------------------------------------------------------------
__global__ __launch_bounds__(256) void gemm_nt1_64(
    const short* __restrict__ A, const short* __restrict__ B,
    const float* __restrict__ bias, float* __restrict__ C,
    int N, int K) {
  __shared__ short As[2][128 * 32];
  __shared__ short Bs[2][64 * 32];
  const int tid = threadIdx.x;
  const int w = tid >> 6, lane = tid & 63;
  const int l16 = lane & 15, quad = lane >> 4;

  const int b = blockIdx.x;
  const int r = b & 7, ri = b >> 3;          // region = XCD, ri 0..63
  const int bx = (r & 3) * 8 + ri % 8;       // 0..31  (N/64 = 32 tiles)
  const int by = (r >> 2) * 8 + ri / 8;      // 0..15  (M/128 = 16 tiles)
  const int bm = by * 128;
  const int bn = bx * 64;

  const int drow0 = w * 16 + (lane >> 2);
  const int drow1 = drow0 + 64;
  const int slot = lane & 3;
  const int ch0 = slot ^ ((drow0 >> 1) & 3);
  const int ch1 = slot ^ ((drow1 >> 1) & 3);
  const short* gA0 = &A[(size_t)(bm + drow0) * K + ch0 * 8];
  const short* gA1 = &A[(size_t)(bm + drow1) * K + ch1 * 8];
  const short* gB0 = &B[(size_t)(bn + drow0) * K + ch0 * 8];
  const int dA0 = (w * 16) * 32, dA1 = (64 + w * 16) * 32;

  const int wm = (w & 1) * 64, wn = (w >> 1) * 32;
  int offA[4], offB[2];
#pragma unroll
  for (int i = 0; i < 4; ++i) {
    int R = wm + i * 16 + l16;
    offA[i] = R * 32 + (quad ^ ((R >> 1) & 3)) * 8;
  }
#pragma unroll
  for (int j = 0; j < 2; ++j) {
    int R = wn + j * 16 + l16;
    offB[j] = R * 32 + (quad ^ ((R >> 1) & 3)) * 8;
  }

  f32x4 acc[4][2];
#pragma unroll
  for (int i = 0; i < 4; ++i)
#pragma unroll
    for (int j = 0; j < 2; ++j)
#pragma unroll
      for (int e = 0; e < 4; ++e) acc[i][j][e] = 0.f;

  const int T = K / 32;
  dma16(gA0, &As[0][dA0]);
  dma16(gA1, &As[0][dA1]);
  dma16(gB0, &Bs[0][dA0]);
  __syncthreads();

  for (int t = 0; t < T; ++t) {
    const int cur = t & 1, nxt = cur ^ 1;
    if (t + 1 < T) {
      const int ko = (t + 1) * 32;
      dma16(gA0 + ko, &As[nxt][dA0]);
      dma16(gA1 + ko, &As[nxt][dA1]);
      dma16(gB0 + ko, &Bs[nxt][dA0]);
    }
    short8 af[4], bf[2];
#pragma unroll
    for (int i = 0; i < 4; ++i) af[i] = *(const short8*)&As[cur][offA[i]];
#pragma unroll
    for (int j = 0; j < 2; ++j) bf[j] = *(const short8*)&Bs[cur][offB[j]];
#pragma unroll
    for (int i = 0; i < 4; ++i)
#pragma unroll
      for (int j = 0; j < 2; ++j)
        acc[i][j] = __builtin_amdgcn_mfma_f32_16x16x32_bf16(af[i], bf[j], acc[i][j], 0, 0, 0);
    __syncthreads();
  }

#pragma unroll
  for (int i = 0; i < 4; ++i) {
    const int row0 = bm + wm + i * 16 + quad * 4;
#pragma unroll
    for (int j = 0; j < 2; ++j) {
      const int col = bn + wn + j * 16 + l16;
      const float bv = bias[col];
#pragma unroll
      for (int e = 0; e < 4; ++e)
        C[(size_t)(row0 + e) * N + col] = acc[i][j][e] + bv;
    }
  }
}

// ---------------------------------------------------------------------------
// MFMA flash attention v10 (verified 69.4us): v8 structure + zero-C MFMA
// init + s_setprio around MFMA clusters.
// ---------------------------------------------------------------------------
__global__ __launch_bounds__(256, 4) void flash10(
    const short* __restrict__ Qrm, const short* __restrict__ Krm,
    const short* __restrict__ Vt, short* __restrict__ Oh) {
  const int qt = blockIdx.x, h = blockIdx.y;
  const int kvh = h >> 2;
  const int tid = threadIdx.x;
  const int w = tid >> 6, lane = tid & 63;
  const int l16 = lane & 15, quad = lane >> 4;

  __shared__ short Ks[2][64 * 64];
  __shared__ short Vs[2][64 * 64];
  __shared__ short Ps[64 * 64];

  const short* Vh = Vt + (size_t)kvh * 64 * S_LEN;
  const int qr = qt * 64 + w * 16 + l16;

  short8 qf0 = *(const short8*)&Qrm[(size_t)qr * D_MODEL + h * 64 + quad * 8];
  short8 qf1 = *(const short8*)&Qrm[(size_t)qr * D_MODEL + h * 64 + 32 + quad * 8];

  short8 ones;
#pragma unroll
  for (int e = 0; e < 8; ++e) ones[e] = (short)0x3F80;   // bf16 1.0

  f32x4 fz;
#pragma unroll
  for (int e = 0; e < 4; ++e) fz[e] = 0.f;

  const int drow = lane >> 3;
  const int ch = (lane & 7) ^ drow;
  const short* gK = &Krm[(size_t)(w * 16 + drow) * 512 + kvh * 64 + ch * 8];
  const short* gV = &Vh[(size_t)(w * 16 + drow) * S_LEN + ch * 8];

  const int sl0 = quad ^ (l16 & 7);
  int offT[4][2];
#pragma unroll
  for (int m = 0; m < 4; ++m) {
    offT[m][0] = (m * 16 + l16) * 64 + sl0 * 8;
    offT[m][1] = (m * 16 + l16) * 64 + (sl0 ^ 4) * 8;
  }

  const int prow = (w * 16 + l16) * 64;
  const int pswz = (l16 & 7) << 1;
  int pwr[4];
#pragma unroll
  for (int m = 0; m < 4; ++m) pwr[m] = prow + ((4 * m + quad) ^ pswz) * 4;
  const int prd0 = prow + ((2 * quad) ^ pswz) * 4;
  const int prd1 = prow + ((8 + 2 * quad) ^ pswz) * 4;

  f32x4 accl;
#pragma unroll
  for (int e = 0; e < 4; ++e) accl[e] = 0.f;
  f32x4 acco[4];
#pragma unroll
  for (int m = 0; m < 4; ++m)
#pragma unroll
    for (int e = 0; e < 4; ++e) acco[m][e] = 0.f;

  dma16(gK,               &Ks[0][(w * 16) * 64]);
  dma16(gK + 8 * 512,     &Ks[0][(w * 16 + 8) * 64]);
  dma16(gV,               &Vs[0][(w * 16) * 64]);
  dma16(gV + 8 * S_LEN,   &Vs[0][(w * 16 + 8) * 64]);
  __syncthreads();

  for (int t = 0; t < 32; ++t) {
    const int cur = t & 1, nxt = cur ^ 1;
    if (t + 1 < 32) {
      const short* gKn = gK + (size_t)(t + 1) * 64 * 512;
      const short* gVn = gV + (t + 1) * 64;
      dma16(gKn,             &Ks[nxt][(w * 16) * 64]);
      dma16(gKn + 8 * 512,   &Ks[nxt][(w * 16 + 8) * 64]);
      dma16(gVn,             &Vs[nxt][(w * 16) * 64]);
      dma16(gVn + 8 * S_LEN, &Vs[nxt][(w * 16 + 8) * 64]);
    }

    const short* kc = Ks[cur];
    f32x4 accs[4];
    __builtin_amdgcn_s_setprio(1);
#pragma unroll
    for (int m = 0; m < 4; ++m) {
      short8 k0 = *(const short8*)&kc[offT[m][0]];
      short8 k1 = *(const short8*)&kc[offT[m][1]];
      accs[m] = __builtin_amdgcn_mfma_f32_16x16x32_bf16(k0, qf0, fz, 0, 0, 0);
      accs[m] = __builtin_amdgcn_mfma_f32_16x16x32_bf16(k1, qf1, accs[m], 0, 0, 0);
    }
    __builtin_amdgcn_s_setprio(0);

#pragma unroll
    for (int m = 0; m < 4; ++m) {
      float p0 = exp2f(accs[m][0]);
      float p1 = exp2f(accs[m][1]);
      float p2 = exp2f(accs[m][2]);
      float p3 = exp2f(accs[m][3]);
      unsigned u01 = __builtin_amdgcn_perm(__float_as_uint(p1), __float_as_uint(p0), 0x07060302u);
      unsigned u23 = __builtin_amdgcn_perm(__float_as_uint(p3), __float_as_uint(p2), 0x07060302u);
      *(uint2*)&Ps[pwr[m]] = make_uint2(u01, u23);
    }

    short8 pf0 = *(const short8*)&Ps[prd0];
    short8 pf1 = *(const short8*)&Ps[prd1];
    __builtin_amdgcn_s_setprio(1);
    accl = __builtin_amdgcn_mfma_f32_16x16x32_bf16(ones, pf0, accl, 0, 0, 0);
    accl = __builtin_amdgcn_mfma_f32_16x16x32_bf16(ones, pf1, accl, 0, 0, 0);
    const short* vc = Vs[cur];
#pragma unroll
    for (int m = 0; m < 4; ++m) {
      short8 v0 = *(const short8*)&vc[offT[m][0]];
      short8 v1 = *(const short8*)&vc[offT[m][1]];
      acco[m] = __builtin_amdgcn_mfma_f32_16x16x32_bf16(v0, pf0, acco[m], 0, 0, 0);
      acco[m] = __builtin_amdgcn_mfma_f32_16x16x32_bf16(v1, pf1, acco[m], 0, 0, 0);
    }
    __builtin_amdgcn_s_setprio(0);

    __syncthreads();
  }

  const float inv = 1.f / accl[0];
#pragma unroll
  for (int m = 0; m < 4; ++m) {
    short4 h4;
    h4.x = bf16_rne(acco[m][0] * inv);
    h4.y = bf16_rne(acco[m][1] * inv);
    h4.z = bf16_rne(acco[m][2] * inv);
    h4.w = bf16_rne(acco[m][3] * inv);
    const size_t base = (size_t)qr * D_MODEL + h * 64 + m * 16 + quad * 4;
    *(short4*)&Oh[base] = h4;
  }
}

// ---------------------------------------------------------------------------
extern "C" void kernel_launch(void* const* d_in, const int* in_sizes, int n_in,
                              void* d_out, int out_size, void* d_ws, size_t ws_size,
                              hipStream_t stream) {
  const float* x     = (const float*)d_in[0];
  const float* W_q   = (const float*)d_in[1];
  const float* b_q   = (const float*)d_in[2];
  const float* W_kv  = (const float*)d_in[3];
  const float* b_kv  = (const float*)d_in[4];
  const float* W_out = (const float*)d_in[5];
  const float* b_out = (const float*)d_in[6];
  float* out = (float*)d_out;

  char* ws = (char*)d_ws;                        // ~41 MB used
  short* xh    = (short*)(ws);                   //  8 MB
  short* Wqh   = (short*)(ws + (8u << 20));      //  8 MB
  short* Wkvh  = (short*)(ws + (16u << 20));     //  4 MB
  short* Woh   = (short*)(ws + (20u << 20));     //  8 MB
  short* Qrm   = (short*)(ws + (28u << 20));     //  8 MB bf16 [2048][2048]
  short* Krm   = (short*)(ws + (36u << 20));     //  2 MB bf16 [2048][512]
  short* Vtb   = (short*)(ws + (38u << 20));     //  2 MB bf16 [8][64][2048]
  float* freqTab = (float*)(ws + (40u << 20));   //  128 B
  short* Ath   = xh;   // x dead after gemm_qkv_rope

  // fused conversion + freq-table launch
  cvt_all<<<7168, 256, 0, stream>>>(x, xh, W_q, Wqh, W_kv, Wkvh, W_out, Woh,
                                    freqTab);

  // QKV projection, XCD-swizzled 1D grid (768 blocks)
  gemm_qkv_rope<<<768, 256, 0, stream>>>(
      xh, Wqh, Wkvh, b_q, b_kv, freqTab, Qrm, Krm, Vtb);

  flash10<<<dim3(S_LEN / 64, Q_HEADS), 256, 0, stream>>>(Qrm, Krm, Vtb, Ath);

  // out-projection, BN=64, XCD-swizzled 1D grid (512 blocks, 2 blocks/CU)
  gemm_nt1_64<<<512, 256, 0, stream>>>(Ath, Woh, b_out, out, 2048, 2048);
}